// Round 10
// baseline (331.781 us; speedup 1.0000x reference)
//
#include <hip/hip_runtime.h>
#include <hip/hip_bf16.h>
#include <stdint.h>

typedef __attribute__((ext_vector_type(8))) short bf16x8;
typedef __attribute__((ext_vector_type(4))) float f32x4;
typedef __attribute__((ext_vector_type(4))) float floatv4;
typedef __attribute__((ext_vector_type(8))) unsigned short ushortx8;

// fp32 -> bf16 round-to-nearest-even (finite inputs)
__device__ __forceinline__ unsigned short f2bf(float f) {
  union { float f; uint32_t u; } c; c.f = f;
  uint32_t u = c.u;
  uint32_t r = (u + 0x7FFFu + ((u >> 16) & 1u)) >> 16;
  return (unsigned short)r;
}

__global__ void cvt_f32_to_bf16(const float* __restrict__ src,
                                unsigned short* __restrict__ dst,
                                size_t n8) {
  size_t i = (size_t)blockIdx.x * blockDim.x + threadIdx.x;
  size_t stride = (size_t)gridDim.x * blockDim.x;
  for (size_t j = i; j < n8; j += stride) {
    floatv4 v0 = ((const floatv4*)src)[j * 2];
    floatv4 v1 = ((const floatv4*)src)[j * 2 + 1];
    ushortx8 o;
    o[0] = f2bf(v0[0]); o[1] = f2bf(v0[1]); o[2] = f2bf(v0[2]); o[3] = f2bf(v0[3]);
    o[4] = f2bf(v1[0]); o[5] = f2bf(v1[1]); o[6] = f2bf(v1[2]); o[7] = f2bf(v1[3]);
    ((ushortx8*)dst)[j] = o;
  }
}

// ----------- 256x128 triple-buffered k-split pipelined bf16 GEMM -----------
// C = A * B^T + bias. 512 threads = 8 waves (4M x 2N), per-wave output 64x64,
// acc = 16 x f32x4 = 64 AGPR -> ~190 arch-VGPR headroom for the pipeline.
// LDS 144 KiB = 3 buffers x (A 256x64 + B 128x64) bf16. Triple buffering:
// tile t+2 staged into buf (t+2)%3 = tile t-1's buffer (reads retired >=1
// barrier earlier) -> no stage/read WAR by construction.
// Per K-tile, 2 phases (k-split at K=32):
//   P0(t): read k1-frags(t) [grind under MFMA]; stage A(t+2);
//          16 MFMA on k0-frags (read in P1(t-1)); VMCNT(4) [tile t+1 done]; BAR
//   P1(t): read k0-frags(t+1) from buf (t+1)%3 [grind under MFMA];
//          stage B(t+2); 16 MFMA on k1-frags; BAR
// vmcnt ledger: entering P0(t): 6 outstanding {A,B}(t+1); +4 A(t+2) -> 10;
// VMCNT(4) completes exactly tile t+1's 6. Tail: VMCNT(0) at t=Kt-2.
// Read-side XOR swizzle as before; inverse pre-applied to global source.

#define BAR()    do { asm volatile("" ::: "memory"); __builtin_amdgcn_s_barrier(); asm volatile("" ::: "memory"); } while (0)
#define VMCNT(n) asm volatile("s_waitcnt vmcnt(" #n ")" ::: "memory")

// stage one 128x64 half-tile (16 KiB) at LDS element-offset lbase
#define STG(ptr, lbase, rcb, k0_) do {                                             \
    _Pragma("unroll")                                                              \
    for (int _l = 0; _l < 2; ++_l) {                                               \
      const int _idx = _l * 512 + tid;                                             \
      const int _r = _idx >> 3;                                                    \
      const int _ks = ((_idx & 7) * 8) ^ ((_r & 7) * 8);                           \
      __builtin_amdgcn_global_load_lds(                                            \
        (const __attribute__((address_space(1))) void*)((ptr) + (size_t)((rcb) + _r) * K + (k0_) + _ks), \
        (__attribute__((address_space(3))) void*)&lds[(lbase) + (unsigned)((_l * 512 + widx * 64) * 8)], \
        16, 0, 0);                                                                 \
    }                                                                              \
  } while (0)

// read one k-half's fragments: 4 A-frags + 4 B-frags (8 x ds_read_b128)
#define READ_KH(aF, bF, bo, koff)                                                  \
  _Pragma("unroll")                                                                \
  for (int mi = 0; mi < 4; ++mi)                                                   \
    aF[mi] = *(const bf16x8*)&lds[(bo) + arow0 + (unsigned)(mi * 1024) + (koff)];  \
  _Pragma("unroll")                                                                \
  for (int ni = 0; ni < 4; ++ni)                                                   \
    bF[ni] = *(const bf16x8*)&lds[(bo) + brow0 + (unsigned)(ni * 1024) + (koff)];

// 16 MFMA: 4mi x 4ni, one k-half
#define MF16(aF, bF)                                                               \
  __builtin_amdgcn_s_setprio(1);                                                   \
  _Pragma("unroll")                                                                \
  for (int mi = 0; mi < 4; ++mi)                                                   \
    _Pragma("unroll")                                                              \
    for (int ni = 0; ni < 4; ++ni)                                                 \
      acc[mi][ni] = __builtin_amdgcn_mfma_f32_16x16x32_bf16(aF[mi], bF[ni], acc[mi][ni], 0, 0, 0); \
  __builtin_amdgcn_s_setprio(0);

__global__ __launch_bounds__(512, 2)
void gemm_km(const unsigned short* __restrict__ Ag,
             const unsigned short* __restrict__ Bg,
             const float* __restrict__ bias, float* __restrict__ C,
             int M, int N, int K)
{
  __shared__ __attribute__((aligned(128))) unsigned short lds[73728];  // 144 KiB
  const int tid  = threadIdx.x;
  const int lane = tid & 63;
  const int widx = tid >> 6;              // 8 waves
  const int wm   = widx >> 1;             // 0..3 (M)
  const int wn   = widx & 1;              // 0..1 (N)

  int bid = blockIdx.x;
  const int nwg = gridDim.x;
  if ((nwg & 7) == 0) { const int cpx = nwg >> 3; bid = (bid & 7) * cpx + (bid >> 3); }
  const int nTN = N >> 7;                 // n-fast: consecutive bids share A-panel
  const int tm = bid / nTN, tn = bid - tm * nTN;
  const int row0 = tm << 8, col0 = tn << 7;

  const int l15 = lane & 15, l16 = lane >> 4;
  const unsigned m7    = (unsigned)((lane & 7) * 8);
  const unsigned koff0 = ((unsigned)(l16 * 8)) ^ m7;       // k 0..31 frag
  const unsigned koff1 = ((unsigned)(32 + l16 * 8)) ^ m7;  // k 32..63 frag

  const int Kt = K >> 6;

  // per-wave LDS row bases (elements). A: region (wm>>1), row (wm&1)*64+mi*16+l15.
  const unsigned arow0 = (unsigned)((wm >> 1) * 8192 + (((wm & 1) * 64) + l15) * 64);
  const unsigned brow0 = (unsigned)(16384 + (wn * 64 + l15) * 64);

  f32x4  acc[4][4] = {};
  bf16x8 aK0[4], bK0[4], aK1[4], bK1[4];

  // buffer rotation: cr = buf(t), nx = buf(t+1), st = buf(t+2)
  unsigned cr = 0, nx = 24576, st = 49152;

  // ---- prologue: stage tile0, tile1; complete tile0; pre-read its k0 frags
  STG(Ag, 0u,          row0,       0); STG(Ag, 8192u,          row0 + 128, 0);
  STG(Bg, 16384u,      col0,       0);
  if (Kt > 1) {
    STG(Ag, 24576u,    row0,      64); STG(Ag, 24576u + 8192u, row0 + 128, 64);
    STG(Bg, 24576u + 16384u, col0, 64);
    VMCNT(6);                // tile0's 6 loads complete; tile1's 6 in flight
  } else {
    VMCNT(0);
  }
  BAR();                     // all waves drained tile0
  READ_KH(aK0, bK0, 0u, koff0);

  for (int t = 0; t < Kt; ++t) {
    const int k2 = (t + 2) << 6;

    // ---- P0: read k1(t) [grinds under MFMA(k0)]; stage A(t+2); MFMA(k0);
    //          VMCNT completes tile t+1; BAR
    READ_KH(aK1, bK1, cr, koff1);
    if (t < Kt - 2) { STG(Ag, st, row0, k2); STG(Ag, st + 8192u, row0 + 128, k2); }
    MF16(aK0, bK0);
    if (t < Kt - 2)       { VMCNT(4); }  // completes tile t+1's 6; A(t+2)'s 4 in flight
    else if (t == Kt - 2) { VMCNT(0); }  // drain before final tile
    BAR();

    // ---- P1: read k0(t+1) from nx [grinds under MFMA(k1)]; stage B(t+2);
    //          MFMA(k1); BAR
    if (t < Kt - 1) { READ_KH(aK0, bK0, nx, koff0); }
    if (t < Kt - 2) { STG(Bg, st + 16384u, col0, k2); }
    MF16(aK1, bK1);
    BAR();

    const unsigned tmp = cr; cr = nx; nx = st; st = tmp;   // rotate buffers
  }

  // ---- epilogue: C/D layout col=lane&15, row=(lane>>4)*4+j
  #pragma unroll
  for (int ni = 0; ni < 4; ++ni) {
    const int col = col0 + wn * 64 + ni * 16 + l15;
    const float bv = bias[col];
    #pragma unroll
    for (int mi = 0; mi < 4; ++mi) {
      #pragma unroll
      for (int j = 0; j < 4; ++j) {
        const int row = row0 + wm * 64 + mi * 16 + l16 * 4 + j;
        C[(size_t)row * N + col] = acc[mi][ni][j] + bv;
      }
    }
  }
}

// ---------------- fallback: 128x128 2-phase kernel (round-1, verified) ----------------
template<bool BF16SRC>
__global__ __launch_bounds__(256)
void gemm_bt_kernel(const void* __restrict__ Ap, const void* __restrict__ Bp,
                    const float* __restrict__ bias, float* __restrict__ C,
                    int M, int N, int K)
{
  constexpr int BM = 128, BN = 128, BK = 64;
  __shared__ unsigned short As[BM * BK];
  __shared__ unsigned short Bs[BN * BK];

  const int nTN = N / BN;
  int bid = blockIdx.x;
  const int nwg = gridDim.x;
  if ((nwg & 7) == 0) { const int cpx = nwg >> 3; bid = (bid & 7) * cpx + (bid >> 3); }
  const int tm = bid / nTN, tn = bid % nTN;
  const int row0 = tm * BM, col0 = tn * BN;

  const int tid  = threadIdx.x;
  const int lane = tid & 63;
  const int wid  = tid >> 6;
  const int wm   = wid >> 1;
  const int wn   = wid & 1;

  f32x4 acc[4][4] = {};

  const unsigned short* A16 = (const unsigned short*)Ap;
  const unsigned short* B16 = (const unsigned short*)Bp;
  const float* A32 = (const float*)Ap;
  const float* B32 = (const float*)Bp;

  for (int k0 = 0; k0 < K; k0 += BK) {
    if constexpr (BF16SRC) {
      #pragma unroll
      for (int j = 0; j < 4; ++j) {
        const int c  = wid * 4 + j;
        const int r  = c * 8 + (lane >> 3);
        const int kk = (lane & 7) * 8;
        __builtin_amdgcn_global_load_lds(
            (const __attribute__((address_space(1))) void*)(A16 + (size_t)(row0 + r) * K + k0 + kk),
            (__attribute__((address_space(3))) void*)(&As[c * 512]), 16, 0, 0);
      }
      #pragma unroll
      for (int j = 0; j < 4; ++j) {
        const int c  = wid * 4 + j;
        const int r  = c * 8 + (lane >> 3);
        const int kk = (lane & 7) * 8;
        __builtin_amdgcn_global_load_lds(
            (const __attribute__((address_space(1))) void*)(B16 + (size_t)(col0 + r) * K + k0 + kk),
            (__attribute__((address_space(3))) void*)(&Bs[c * 512]), 16, 0, 0);
      }
    } else {
      #pragma unroll
      for (int j = 0; j < 4; ++j) {
        const int e = (j * 256 + tid) * 8;
        const int r = e >> 6, kk = e & 63;
        floatv4 v0 = *(const floatv4*)&A32[(size_t)(row0 + r) * K + k0 + kk];
        floatv4 v1 = *(const floatv4*)&A32[(size_t)(row0 + r) * K + k0 + kk + 4];
        ushortx8 o;
        o[0] = f2bf(v0[0]); o[1] = f2bf(v0[1]); o[2] = f2bf(v0[2]); o[3] = f2bf(v0[3]);
        o[4] = f2bf(v1[0]); o[5] = f2bf(v1[1]); o[6] = f2bf(v1[2]); o[7] = f2bf(v1[3]);
        *(ushortx8*)&As[e] = o;
      }
      #pragma unroll
      for (int j = 0; j < 4; ++j) {
        const int e = (j * 256 + tid) * 8;
        const int r = e >> 6, kk = e & 63;
        floatv4 v0 = *(const floatv4*)&B32[(size_t)(col0 + r) * K + k0 + kk];
        floatv4 v1 = *(const floatv4*)&B32[(size_t)(col0 + r) * K + k0 + kk + 4];
        ushortx8 o;
        o[0] = f2bf(v0[0]); o[1] = f2bf(v0[1]); o[2] = f2bf(v0[2]); o[3] = f2bf(v0[3]);
        o[4] = f2bf(v1[0]); o[5] = f2bf(v1[1]); o[6] = f2bf(v1[2]); o[7] = f2bf(v1[3]);
        *(ushortx8*)&Bs[e] = o;
      }
    }
    __syncthreads();

    #pragma unroll
    for (int kk = 0; kk < BK / 32; ++kk) {
      const int ko = kk * 32 + (lane >> 4) * 8;
      bf16x8 a[4], b[4];
      #pragma unroll
      for (int mi = 0; mi < 4; ++mi)
        a[mi] = *(const bf16x8*)&As[(wm * 64 + mi * 16 + (lane & 15)) * BK + ko];
      #pragma unroll
      for (int ni = 0; ni < 4; ++ni)
        b[ni] = *(const bf16x8*)&Bs[(wn * 64 + ni * 16 + (lane & 15)) * BK + ko];
      #pragma unroll
      for (int mi = 0; mi < 4; ++mi)
        #pragma unroll
        for (int ni = 0; ni < 4; ++ni)
          acc[mi][ni] = __builtin_amdgcn_mfma_f32_16x16x32_bf16(a[mi], b[ni], acc[mi][ni], 0, 0, 0);
    }
    __syncthreads();
  }

  #pragma unroll
  for (int mi = 0; mi < 4; ++mi) {
    #pragma unroll
    for (int ni = 0; ni < 4; ++ni) {
      const int col = col0 + wn * 64 + ni * 16 + (lane & 15);
      const float bv = bias[col];
      #pragma unroll
      for (int j = 0; j < 4; ++j) {
        const int row = row0 + wm * 64 + mi * 16 + (lane >> 4) * 4 + j;
        C[(size_t)row * N + col] = acc[mi][ni][j] + bv;
      }
    }
  }
}

extern "C" void kernel_launch(void* const* d_in, const int* in_sizes, int n_in,
                              void* d_out, int out_size, void* d_ws, size_t ws_size,
                              hipStream_t stream) {
  const float* x = (const float*)d_in[0];
  const float* w = (const float*)d_in[1];
  const float* b = (const float*)d_in[2];
  float* out = (float*)d_out;

  const int N = in_sizes[2];            // 4096
  const int K = in_sizes[1] / N;        // 4096
  const int M = in_sizes[0] / K;        // 8192

  const size_t needed = ((size_t)M * K + (size_t)N * K) * sizeof(unsigned short);

  if (ws_size >= needed) {
    unsigned short* Abf = (unsigned short*)d_ws;
    unsigned short* Bbf = Abf + (size_t)M * K;
    cvt_f32_to_bf16<<<2048, 256, 0, stream>>>(x, Abf, (size_t)M * K / 8);
    cvt_f32_to_bf16<<<2048, 256, 0, stream>>>(w, Bbf, (size_t)N * K / 8);
    if ((M % 256) == 0 && (N % 128) == 0 && (K % 64) == 0 && K >= 192) {
      const int grid = (M / 256) * (N / 128);
      gemm_km<<<grid, 512, 0, stream>>>(Abf, Bbf, b, out, M, N, K);
    } else {
      const int grid = (M / 128) * (N / 128);
      gemm_bt_kernel<true><<<grid, 256, 0, stream>>>(Abf, Bbf, b, out, M, N, K);
    }
  } else {
    const int grid = (M / 128) * (N / 128);
    gemm_bt_kernel<false><<<grid, 256, 0, stream>>>(x, w, b, out, M, N, K);
  }
}

// Round 11
// 306.552 us; speedup vs baseline: 1.0823x; 1.0823x over previous
//
#include <hip/hip_runtime.h>
#include <hip/hip_bf16.h>
#include <stdint.h>

typedef __attribute__((ext_vector_type(8))) short bf16x8;
typedef __attribute__((ext_vector_type(4))) float f32x4;
typedef __attribute__((ext_vector_type(4))) float floatv4;
typedef __attribute__((ext_vector_type(8))) unsigned short ushortx8;

// fp32 -> bf16 round-to-nearest-even (finite inputs)
__device__ __forceinline__ unsigned short f2bf(float f) {
  union { float f; uint32_t u; } c; c.f = f;
  uint32_t u = c.u;
  uint32_t r = (u + 0x7FFFu + ((u >> 16) & 1u)) >> 16;
  return (unsigned short)r;
}

__global__ void cvt_f32_to_bf16(const float* __restrict__ src,
                                unsigned short* __restrict__ dst,
                                size_t n8) {
  size_t i = (size_t)blockIdx.x * blockDim.x + threadIdx.x;
  size_t stride = (size_t)gridDim.x * blockDim.x;
  for (size_t j = i; j < n8; j += stride) {
    floatv4 v0 = ((const floatv4*)src)[j * 2];
    floatv4 v1 = ((const floatv4*)src)[j * 2 + 1];
    ushortx8 o;
    o[0] = f2bf(v0[0]); o[1] = f2bf(v0[1]); o[2] = f2bf(v0[2]); o[3] = f2bf(v0[3]);
    o[4] = f2bf(v1[0]); o[5] = f2bf(v1[1]); o[6] = f2bf(v1[2]); o[7] = f2bf(v1[3]);
    ((ushortx8*)dst)[j] = o;
  }
}

// ---------------- 4-barrier 256x256 bf16 GEMM (C = A * B^T + bias) ----------------
// 512 threads = 8 waves (2M x 4N), per-wave output 128x64.
// LDS 128 KiB: A[2buf][2half][128][64] + B[2buf][2half][128][64], bf16,
// read-side XOR swizzle (inverse pre-applied to global source of global_load_lds).
//
// Round-8 ledger with BALANCED reads 8/4/8/4:
//  P0: read a0(8) same-phase; stage B_s0(t+1); Q(a0,b0) [b0 read at P3(t-1)]; BAR
//  P1: read b1(4); Q(a0,b1); BAR
//  P2: read a1(8); Q(a1,b1); BAR
//  P3: stage B_s1/A_s0/A_s1(t+2); VMCNT(6); BAR; Q(a1,b0); read b0(t+1)
//      [read AFTER the all-waves VMCNT+BAR (vmcnt is per-wave!) and after
//       Q's last use of old b0; no end barrier — back-edge region audited]
// vmcnt ledger: entering P0 = 6 {B_s1,A_s0,A_s1}(t+1); +2 (B_s0(t+1)) = 8;
// +6 (t+2) = 14; VMCNT(6) completes the 8 oldest = tile t+1 exactly (incl. its
// B_s0). Tails: VMCNT(0) at t=Kt-2; no stage/read at t=Kt-1.
// WAR: every staged region's ds_reads retired >=1 barrier earlier (audited).

#define BAR()    do { asm volatile("" ::: "memory"); __builtin_amdgcn_s_barrier(); asm volatile("" ::: "memory"); } while (0)
#define VMCNT(n) asm volatile("s_waitcnt vmcnt(" #n ")" ::: "memory")

// stage one 128x64 half-tile (16 KiB) via 2x global_load_lds(16B)/thread.
// sp = precomputed per-thread source base (matrix + row*K + swizzled k), hoff
// selects the half; per-call adds only (t<<6) + l*64K.
#define STG(sp, lbase, h, t_) do {                                                 \
    const unsigned _lb = (lbase) + (unsigned)((((t_) & 1) * 2 + (h)) * 8192);      \
    const size_t _k0 = (size_t)((t_) << 6);                                        \
    _Pragma("unroll")                                                              \
    for (int _l = 0; _l < 2; ++_l) {                                               \
      __builtin_amdgcn_global_load_lds(                                            \
        (const __attribute__((address_space(1))) void*)((sp) + (size_t)(h) * hoff + (size_t)_l * l1off + _k0), \
        (__attribute__((address_space(3))) void*)&lds[_lb + (unsigned)((_l * 512 + widx * 64) * 8)], \
        16, 0, 0);                                                                 \
    }                                                                              \
  } while (0)

// read A quad q (8 x ds_read_b128): rows q*64 + mi*16 + l15 of wave's A-half
#define READ_A(dst, q, bo)                                                         \
  _Pragma("unroll")                                                                \
  for (int mi = 0; mi < 4; ++mi) {                                                 \
    const unsigned rb = Abase + (bo) + (unsigned)((((q) * 64) + mi * 16 + l15) * 64); \
    dst[mi * 2 + 0] = *(const bf16x8*)&lds[rb + koff0];                            \
    dst[mi * 2 + 1] = *(const bf16x8*)&lds[rb + koff1];                            \
  }

// read B n-half h (4 x ds_read_b128): rows brow + h*32 + ni*16 + l15 of wave's B-half
#define READ_B(dst, h, bo)                                                         \
  _Pragma("unroll")                                                                \
  for (int ni = 0; ni < 2; ++ni) {                                                 \
    const unsigned rb = Bbase + (bo) + (brow + (unsigned)((h) * 32 + ni * 16 + l15)) * 64u; \
    dst[ni * 2 + 0] = *(const bf16x8*)&lds[rb + koff0];                            \
    dst[ni * 2 + 1] = *(const bf16x8*)&lds[rb + koff1];                            \
  }

// one C-quadrant (q = M-quad, h = N-half) x K=64: 4mi x 2ni x 2kk = 16 MFMA
#define QUAD(aF, bF, q, h)                                                         \
  _Pragma("unroll")                                                                \
  for (int mi = 0; mi < 4; ++mi) {                                                 \
    _Pragma("unroll")                                                              \
    for (int ni = 0; ni < 2; ++ni) {                                               \
      acc[(q)*4+mi][(h)*2+ni] = __builtin_amdgcn_mfma_f32_16x16x32_bf16(           \
          aF[mi*2+0], bF[ni*2+0], acc[(q)*4+mi][(h)*2+ni], 0, 0, 0);               \
      acc[(q)*4+mi][(h)*2+ni] = __builtin_amdgcn_mfma_f32_16x16x32_bf16(           \
          aF[mi*2+1], bF[ni*2+1], acc[(q)*4+mi][(h)*2+ni], 0, 0, 0);               \
    }                                                                              \
  }

__global__ __launch_bounds__(512, 2)
void gemm8p_bt(const unsigned short* __restrict__ Ag,
               const unsigned short* __restrict__ Bg,
               const float* __restrict__ bias, float* __restrict__ C,
               int M, int N, int K)
{
  __shared__ __attribute__((aligned(128))) unsigned short lds[65536];   // 128 KiB
  const int tid  = threadIdx.x;
  const int lane = tid & 63;
  const int widx = tid >> 6;              // 8 waves
  const int wm   = widx >> 2;             // 0..1  (M)
  const int wn   = widx & 3;              // 0..3  (N)

  int bid = blockIdx.x;
  const int nwg = gridDim.x;
  if ((nwg & 7) == 0) { const int cpx = nwg >> 3; bid = (bid & 7) * cpx + (bid >> 3); }
  const int nTN = N >> 8;
  const int tm = bid / nTN, tn = bid - tm * nTN;
  const int row0 = tm << 8, col0 = tn << 8;

  const int l15 = lane & 15, l16 = lane >> 4;
  const unsigned m7    = (unsigned)((lane & 7) * 8);      // per-lane XOR mask (elems)
  const unsigned koff0 = ((unsigned)(l16 * 8)) ^ m7;      // kk=0 swizzled k-offset
  const unsigned koff1 = ((unsigned)(32 + l16 * 8)) ^ m7; // kk=1

  const int Kt = K >> 6;

  const unsigned Abase = (unsigned)(wm * 8192);               // + buf*16384
  const unsigned Bbase = 32768u + (unsigned)((wn >> 1) * 8192);
  const unsigned brow  = (unsigned)((wn & 1) * 64);

  // hoisted staging addressing: per-thread source bases (swizzle pre-applied)
  const int sr = tid >> 3;                                           // 0..63
  const unsigned sks = (unsigned)(((tid & 7) * 8) ^ ((sr & 7) * 8)); // swz k-off
  const size_t l1off = (size_t)64 * K;    // _l=1 -> +64 rows
  const size_t hoff  = (size_t)128 * K;   // half 1 -> +128 rows
  const unsigned short* sA = Ag + (size_t)(row0 + sr) * K + sks;
  const unsigned short* sB = Bg + (size_t)(col0 + sr) * K + sks;

  f32x4 acc[8][4] = {};
  bf16x8 a0[8], a1[8], b0[4], b1[4];

  // ---- prologue: tile0 (4 halves) + {B_s1(1), A_s0(1), A_s1(1)} ----
  // Invariant entering each iteration: 6 in flight = {B_s1,A_s0,A_s1}(t+1).
  STG(sA, 0u,      0, 0);
  STG(sA, 0u,      1, 0);
  STG(sB, 32768u,  0, 0);
  STG(sB, 32768u,  1, 0);
  if (Kt > 1) {
    STG(sB, 32768u, 1, 1);
    STG(sA, 0u,     0, 1);
    STG(sA, 0u,     1, 1);
    VMCNT(6);                 // tile0's 8 loads complete; tile1's 6 in flight
  } else {
    VMCNT(0);
  }
  BAR();                      // ALL waves drained tile0 -> reads below safe
  READ_B(b0, 0, 0u);          // pre-read tile0's b0 (4 reads)

  for (int t = 0; t < Kt; ++t) {
    const unsigned bufo  = (unsigned)((t & 1) * 16384);
    const unsigned nbufo = (unsigned)(((t + 1) & 1) * 16384);

    // ---- P0: read a0(8) same-phase; stage B_s0(t+1); Q(a0,b0); BAR
    READ_A(a0, 0, bufo);
    if (t < Kt - 1) STG(sB, 32768u, 0, t + 1);
    __builtin_amdgcn_s_setprio(1); QUAD(a0, b0, 0, 0); __builtin_amdgcn_s_setprio(0);
    BAR();

    // ---- P1: read b1(4); Q(a0,b1); BAR
    READ_B(b1, 1, bufo);
    __builtin_amdgcn_s_setprio(1); QUAD(a0, b1, 0, 1); __builtin_amdgcn_s_setprio(0);
    BAR();

    // ---- P2: read a1(8); Q(a1,b1); BAR
    READ_A(a1, 1, bufo);
    __builtin_amdgcn_s_setprio(1); QUAD(a1, b1, 1, 1); __builtin_amdgcn_s_setprio(0);
    BAR();

    // ---- P3: stage t+2 (3 halves); VMCNT (tile t+1 landed, every wave); BAR;
    //          Q(a1,b0); read next tile's b0 (grinds under Q, after old-b0 use)
    if (t < Kt - 2) {
      STG(sB, 32768u, 1, t + 2);
      STG(sA, 0u,     0, t + 2);
      STG(sA, 0u,     1, t + 2);
      VMCNT(6);               // completes tile t+1's 4 halves; t+2's 6 in flight
    } else if (t == Kt - 2) {
      VMCNT(0);               // drain: tile Kt-1 fully landed
    }
    BAR();
    __builtin_amdgcn_s_setprio(1); QUAD(a1, b0, 1, 0); __builtin_amdgcn_s_setprio(0);
    if (t < Kt - 1) READ_B(b0, 0, nbufo);
  }

  // ---- epilogue: C/D layout col=lane&15, row=(lane>>4)*4+j
  #pragma unroll
  for (int n = 0; n < 4; ++n) {
    const int col = col0 + wn * 64 + n * 16 + l15;
    const float bv = bias[col];
    #pragma unroll
    for (int mi8 = 0; mi8 < 8; ++mi8) {
      #pragma unroll
      for (int j = 0; j < 4; ++j) {
        const int row = row0 + wm * 128 + mi8 * 16 + l16 * 4 + j;
        C[(size_t)row * N + col] = acc[mi8][n][j] + bv;
      }
    }
  }
}

// ---------------- fallback: 128x128 2-phase kernel (round-1, verified) ----------------
template<bool BF16SRC>
__global__ __launch_bounds__(256)
void gemm_bt_kernel(const void* __restrict__ Ap, const void* __restrict__ Bp,
                    const float* __restrict__ bias, float* __restrict__ C,
                    int M, int N, int K)
{
  constexpr int BM = 128, BN = 128, BK = 64;
  __shared__ unsigned short As[BM * BK];
  __shared__ unsigned short Bs[BN * BK];

  const int nTN = N / BN;
  int bid = blockIdx.x;
  const int nwg = gridDim.x;
  if ((nwg & 7) == 0) { const int cpx = nwg >> 3; bid = (bid & 7) * cpx + (bid >> 3); }
  const int tm = bid / nTN, tn = bid % nTN;
  const int row0 = tm * BM, col0 = tn * BN;

  const int tid  = threadIdx.x;
  const int lane = tid & 63;
  const int wid  = tid >> 6;
  const int wm   = wid >> 1;
  const int wn   = wid & 1;

  f32x4 acc[4][4] = {};

  const unsigned short* A16 = (const unsigned short*)Ap;
  const unsigned short* B16 = (const unsigned short*)Bp;
  const float* A32 = (const float*)Ap;
  const float* B32 = (const float*)Bp;

  for (int k0 = 0; k0 < K; k0 += BK) {
    if constexpr (BF16SRC) {
      #pragma unroll
      for (int j = 0; j < 4; ++j) {
        const int c  = wid * 4 + j;
        const int r  = c * 8 + (lane >> 3);
        const int kk = (lane & 7) * 8;
        __builtin_amdgcn_global_load_lds(
            (const __attribute__((address_space(1))) void*)(A16 + (size_t)(row0 + r) * K + k0 + kk),
            (__attribute__((address_space(3))) void*)(&As[c * 512]), 16, 0, 0);
      }
      #pragma unroll
      for (int j = 0; j < 4; ++j) {
        const int c  = wid * 4 + j;
        const int r  = c * 8 + (lane >> 3);
        const int kk = (lane & 7) * 8;
        __builtin_amdgcn_global_load_lds(
            (const __attribute__((address_space(1))) void*)(B16 + (size_t)(col0 + r) * K + k0 + kk),
            (__attribute__((address_space(3))) void*)(&Bs[c * 512]), 16, 0, 0);
      }
    } else {
      #pragma unroll
      for (int j = 0; j < 4; ++j) {
        const int e = (j * 256 + tid) * 8;
        const int r = e >> 6, kk = e & 63;
        floatv4 v0 = *(const floatv4*)&A32[(size_t)(row0 + r) * K + k0 + kk];
        floatv4 v1 = *(const floatv4*)&A32[(size_t)(row0 + r) * K + k0 + kk + 4];
        ushortx8 o;
        o[0] = f2bf(v0[0]); o[1] = f2bf(v0[1]); o[2] = f2bf(v0[2]); o[3] = f2bf(v0[3]);
        o[4] = f2bf(v1[0]); o[5] = f2bf(v1[1]); o[6] = f2bf(v1[2]); o[7] = f2bf(v1[3]);
        *(ushortx8*)&As[e] = o;
      }
      #pragma unroll
      for (int j = 0; j < 4; ++j) {
        const int e = (j * 256 + tid) * 8;
        const int r = e >> 6, kk = e & 63;
        floatv4 v0 = *(const floatv4*)&B32[(size_t)(col0 + r) * K + k0 + kk];
        floatv4 v1 = *(const floatv4*)&B32[(size_t)(col0 + r) * K + k0 + kk + 4];
        ushortx8 o;
        o[0] = f2bf(v0[0]); o[1] = f2bf(v0[1]); o[2] = f2bf(v0[2]); o[3] = f2bf(v0[3]);
        o[4] = f2bf(v1[0]); o[5] = f2bf(v1[1]); o[6] = f2bf(v1[2]); o[7] = f2bf(v1[3]);
        *(ushortx8*)&Bs[e] = o;
      }
    }
    __syncthreads();

    #pragma unroll
    for (int kk = 0; kk < BK / 32; ++kk) {
      const int ko = kk * 32 + (lane >> 4) * 8;
      bf16x8 a[4], b[4];
      #pragma unroll
      for (int mi = 0; mi < 4; ++mi)
        a[mi] = *(const bf16x8*)&As[(wm * 64 + mi * 16 + (lane & 15)) * BK + ko];
      #pragma unroll
      for (int ni = 0; ni < 4; ++ni)
        b[ni] = *(const bf16x8*)&Bs[(wn * 64 + ni * 16 + (lane & 15)) * BK + ko];
      #pragma unroll
      for (int mi = 0; mi < 4; ++mi)
        #pragma unroll
        for (int ni = 0; ni < 4; ++ni)
          acc[mi][ni] = __builtin_amdgcn_mfma_f32_16x16x32_bf16(a[mi], b[ni], acc[mi][ni], 0, 0, 0);
    }
    __syncthreads();
  }

  #pragma unroll
  for (int mi = 0; mi < 4; ++mi) {
    #pragma unroll
    for (int ni = 0; ni < 4; ++ni) {
      const int col = col0 + wn * 64 + ni * 16 + (lane & 15);
      const float bv = bias[col];
      #pragma unroll
      for (int j = 0; j < 4; ++j) {
        const int row = row0 + wm * 64 + mi * 16 + (lane >> 4) * 4 + j;
        C[(size_t)row * N + col] = acc[mi][ni][j] + bv;
      }
    }
  }
}

extern "C" void kernel_launch(void* const* d_in, const int* in_sizes, int n_in,
                              void* d_out, int out_size, void* d_ws, size_t ws_size,
                              hipStream_t stream) {
  const float* x = (const float*)d_in[0];
  const float* w = (const float*)d_in[1];
  const float* b = (const float*)d_in[2];
  float* out = (float*)d_out;

  const int N = in_sizes[2];            // 4096
  const int K = in_sizes[1] / N;        // 4096
  const int M = in_sizes[0] / K;        // 8192

  const size_t needed = ((size_t)M * K + (size_t)N * K) * sizeof(unsigned short);

  if (ws_size >= needed) {
    unsigned short* Abf = (unsigned short*)d_ws;
    unsigned short* Bbf = Abf + (size_t)M * K;
    cvt_f32_to_bf16<<<2048, 256, 0, stream>>>(x, Abf, (size_t)M * K / 8);
    cvt_f32_to_bf16<<<2048, 256, 0, stream>>>(w, Bbf, (size_t)N * K / 8);
    if ((M % 256) == 0 && (N % 256) == 0 && (K % 64) == 0 && K >= 192) {
      const int grid = (M / 256) * (N / 256);
      gemm8p_bt<<<grid, 512, 0, stream>>>(Abf, Bbf, b, out, M, N, K);
    } else {
      const int grid = (M / 128) * (N / 128);
      gemm_bt_kernel<true><<<grid, 256, 0, stream>>>(Abf, Bbf, b, out, M, N, K);
    }
  } else {
    const int grid = (M / 128) * (N / 128);
    gemm_bt_kernel<false><<<grid, 256, 0, stream>>>(x, w, b, out, M, N, K);
  }
}